// Round 1
// baseline (1638.910 us; speedup 1.0000x reference)
//
#include <hip/hip_runtime.h>

// ClockworkRNN on MI355X.
// One persistent WG per batch column (256 WGs x 512 threads).
// fp16 packed weights, f32 accumulation, clockwork context caching:
//   ctx[j'][r]  = Wh[r, block j'] . H[block j']   (recomputed only when block j' updates)
//   octx[j'][o] = Wo[o, block j'] . H[block j']
// Per step: z_r = Wi_j . x_t + cb[r] + sum_{j'>=j} ctx[j'][r]; H_r = tanh(z_r) for active rows;
//           y_o = tanh(sum_j' octx[j'][o] + wob[o]).

typedef unsigned int u32;
typedef _Float16 f16;
typedef f16 f16x2 __attribute__((ext_vector_type(2)));

#define TT   512
#define BB   256
#define NI_  128
#define NO_  128
#define KK   512

// ws layout (u32 elements)
#define WIP_N  32768   // 8 blocks x [64 rows][64 col-pairs]
#define WHCP_N 73728   // per j': [64*(j'+1) rows][32 col-pairs], offset 1024*j'*(j'+1)
#define WOCP_N 32768   // 8 blocks x [128 rows][32 col-pairs]

#define SMEM_BYTES 141824

__device__ __forceinline__ u32 pk2(float a, float b){
  f16x2 v; v.x = (f16)a; v.y = (f16)b;
  return __builtin_bit_cast(u32, v);
}

__device__ __forceinline__ float tanh_fast(float x){
  // (e^{2x}-1)/(e^{2x}+1) computed as 1 - 2/(e^{2x}+1): exact at saturation, no NaN.
  float e = __expf(2.0f*x);
  return 1.0f - 2.0f/(e + 1.0f);
}

__device__ __forceinline__ float dot2f(u32 a, u32 b, float acc){
  f16x2 x = __builtin_bit_cast(f16x2, a);
  f16x2 y = __builtin_bit_cast(f16x2, b);
  acc = fmaf((float)x.x, (float)y.x, acc);   // -> v_fma_mix_f32
  acc = fmaf((float)x.y, (float)y.y, acc);
  return acc;
}

// One 64-row reduction pass: lane (row = tid>>3, k = tid&7), PC f16-pairs per lane,
// contiguous uint4 (b128) loads. Caller reduces over k with shfl_xor.
template<int PC>
__device__ __forceinline__ float dotpass(const u32* __restrict__ Wrow, const u32* __restrict__ V, int k){
  float a0 = 0.f, a1 = 0.f;
  #pragma unroll
  for (int g = 0; g < PC/4; ++g){
    const uint4 w = *(const uint4*)(Wrow + k*PC + 4*g);
    const uint4 v = *(const uint4*)(V    + k*PC + 4*g);
    a0 = dot2f(w.x, v.x, a0);
    a1 = dot2f(w.y, v.y, a1);
    a0 = dot2f(w.z, v.z, a0);
    a1 = dot2f(w.w, v.w, a1);
  }
  return a0 + a1;
}

__global__ __launch_bounds__(256) void cw_prep(
    const float* __restrict__ Wi, const float* __restrict__ Wh, const float* __restrict__ Wo,
    u32* __restrict__ WiP, u32* __restrict__ WhcP, u32* __restrict__ WocP,
    float* __restrict__ cb, float* __restrict__ wob)
{
  const int NTOT = WIP_N + WHCP_N + WOCP_N + 512 + 128;
  for (int idx = blockIdx.x*blockDim.x + threadIdx.x; idx < NTOT; idx += (int)(gridDim.x*blockDim.x)){
    if (idx < WIP_N){
      int j   = idx >> 12;
      int rem = idx & 4095;
      int r   = 64*j + (rem >> 6);
      int c2  = rem & 63;
      WiP[idx] = pk2(Wi[r*129 + 2*c2], Wi[r*129 + 2*c2 + 1]);
    } else if (idx < WIP_N + WHCP_N){
      int q = idx - WIP_N;
      int jp = 0;
      while (jp < 7 && q >= 1024*(jp+1)*(jp+2)) ++jp;
      int rem = q - 1024*jp*(jp+1);
      int r   = rem >> 5;
      int c2  = rem & 31;
      WhcP[q] = pk2(Wh[r*513 + 64*jp + 2*c2], Wh[r*513 + 64*jp + 2*c2 + 1]);
    } else if (idx < WIP_N + WHCP_N + WOCP_N){
      int q   = idx - WIP_N - WHCP_N;
      int jp  = q >> 12;
      int rem = q & 4095;
      int o   = rem >> 5;
      int c2  = rem & 31;
      WocP[q] = pk2(Wo[o*513 + 64*jp + 2*c2], Wo[o*513 + 64*jp + 2*c2 + 1]);
    } else if (idx < WIP_N + WHCP_N + WOCP_N + 512){
      int r = idx - WIP_N - WHCP_N - WOCP_N;
      cb[r] = Wh[r*513 + 512] + Wi[r*129 + 128];   // combined recurrent + input bias
    } else {
      int o = idx - WIP_N - WHCP_N - WOCP_N - 512;
      wob[o] = Wo[o*513 + 512];
    }
  }
}

__global__ __launch_bounds__(512, 2) void cw_main(
    const float* __restrict__ X,
    const u32* __restrict__ WiP, const u32* __restrict__ WhcP, const u32* __restrict__ WocP,
    const float* __restrict__ cbg, const float* __restrict__ wobg,
    float* __restrict__ Y, float* __restrict__ Hout)
{
  extern __shared__ char smem[];
  u32*   sWi   = (u32*)smem;             // 8192 u32 : Wi blocks 0,1
  u32*   sWhc  = sWi  + 8192;            // 12288    : Whc j'=0,1,2
  u32*   sWoc  = sWhc + 12288;           // 8192     : Woc j'=0,1
  float* sctx  = (float*)(sWoc + 8192);  // 4096 f32 : ctx[8][512]
  float* soctx = sctx + 4096;            // 1024 f32 : octx[8][128]
  float* scb   = soctx + 1024;           // 512
  float* swob  = scb + 512;              // 128
  u32*   sXpk  = (u32*)(swob + 128);     // 512 u32  : packed x, 8 steps x 64 pairs
  f16*   sH    = (f16*)(sXpk + 512);     // 512
  f16*   sHnew = sH + 512;               // 512

  const int tid = (int)threadIdx.x;
  const int b   = (int)blockIdx.x;
  const int k   = tid & 7;
  const int rl  = tid >> 3;

  // prefill LDS weight caches (weights are L2-resident; one-time)
  for (int i = tid; i < 8192;  i += 512) sWi[i]  = WiP[i];
  for (int i = tid; i < 12288; i += 512) sWhc[i] = WhcP[i];
  for (int i = tid; i < 8192;  i += 512) sWoc[i] = WocP[i];
  scb[tid >= 512 ? 0 : tid] = cbg[tid];   // tid in [0,512)
  if (tid < 128) swob[tid] = wobg[tid];
  sH[tid] = (f16)0.f; sHnew[tid] = (f16)0.f;
  for (int i = tid; i < 4096; i += 512) sctx[i] = 0.f;
  for (int i = tid; i < 1024; i += 512) soctx[i] = 0.f;
  __syncthreads();

  const u32* sHnew_u = (const u32*)sHnew;

  for (int chunk = 0; chunk < 64; ++chunk){
    { // stage + pack 8 timesteps of x for this column
      int s  = tid >> 6;
      int i2 = tid & 63;
      int t  = chunk*8 + s;
      const float2 xv = *((const float2*)X + ((size_t)t*BB + b)*64 + i2);
      f16x2 h2; h2.x = (f16)xv.x; h2.y = (f16)xv.y;
      sXpk[s*64 + i2] = __builtin_bit_cast(u32, h2);
    }
    __syncthreads();

    for (int s = 0; s < 8; ++s){
      const int t = chunk*8 + s;
      int nact = (t == 0) ? 8 : (__builtin_ctz(t) + 1);
      if (nact > 8) nact = 8;

      // ---- (a) new H for active rows: z = Wi_j . x_t + cb + suffix-sum of ctx
      for (int j = 0; j < nact; ++j){
        float acc;
        if (j < 2) acc = dotpass<8>(sWi + j*4096 + rl*64, sXpk + s*64, k);
        else       acc = dotpass<8>(WiP + j*4096 + rl*64, sXpk + s*64, k);
        acc += __shfl_xor(acc, 1);
        acc += __shfl_xor(acc, 2);
        acc += __shfl_xor(acc, 4);
        if (k == 0){
          const int r = j*64 + rl;
          float z = acc + scb[r];
          for (int q = j; q < 8; ++q) z += sctx[q*512 + r];
          sHnew[r] = (f16)tanh_fast(z);
        }
      }
      __syncthreads();   // B1: sHnew complete

      // commit active prefix into persistent H (only needed for final output)
      if (tid < nact*64) sH[tid] = sHnew[tid];

      // ---- (c) recompute ctx[j'] for updated blocks (readers: rows < 64*(j'+1))
      for (int jp = 0; jp < nact; ++jp){
        const int off = 1024*jp*(jp+1);
        for (int tau = 0; tau <= jp; ++tau){
          const int r = tau*64 + rl;
          float acc;
          if (jp < 3) acc = dotpass<4>(sWhc + off + r*32, sHnew_u + jp*32, k);
          else        acc = dotpass<4>(WhcP + off + r*32, sHnew_u + jp*32, k);
          acc += __shfl_xor(acc, 1);
          acc += __shfl_xor(acc, 2);
          acc += __shfl_xor(acc, 4);
          if (k == 0) sctx[jp*512 + r] = acc;
        }
      }
      // ---- (d) recompute octx[j'] for updated blocks
      for (int jp = 0; jp < nact; ++jp){
        #pragma unroll
        for (int hh = 0; hh < 2; ++hh){
          const int o = hh*64 + rl;
          float acc;
          if (jp < 2) acc = dotpass<4>(sWoc + jp*4096 + o*32, sHnew_u + jp*32, k);
          else        acc = dotpass<4>(WocP + jp*4096 + o*32, sHnew_u + jp*32, k);
          acc += __shfl_xor(acc, 1);
          acc += __shfl_xor(acc, 2);
          acc += __shfl_xor(acc, 4);
          if (k == 0) soctx[jp*128 + o] = acc;
        }
      }
      __syncthreads();   // B2: sctx/soctx complete

      // ---- (e) output y_t
      if (tid < 128){
        float z = swob[tid];
        #pragma unroll
        for (int jp = 0; jp < 8; ++jp) z += soctx[jp*128 + tid];
        Y[((size_t)t*BB + b)*NO_ + tid] = tanh_fast(z);
      }
    }
  }

  // final hidden state, H is (K, B)
  Hout[(size_t)tid*BB + b] = (float)sH[tid];
}

extern "C" void kernel_launch(void* const* d_in, const int* in_sizes, int n_in,
                              void* d_out, int out_size, void* d_ws, size_t ws_size,
                              hipStream_t stream)
{
  const float* X  = (const float*)d_in[0];
  const float* Wi = (const float*)d_in[1];
  const float* Wh = (const float*)d_in[2];
  const float* Wo = (const float*)d_in[3];

  u32*   WiP  = (u32*)d_ws;
  u32*   WhcP = WiP  + WIP_N;
  u32*   WocP = WhcP + WHCP_N;
  float* cb   = (float*)(WocP + WOCP_N);
  float* wob  = cb + 512;

  float* Y    = (float*)d_out;
  float* Hout = Y + (size_t)TT*BB*NO_;

  const int prep_n = WIP_N + WHCP_N + WOCP_N + 512 + 128;
  hipLaunchKernelGGL(cw_prep, dim3((prep_n + 255)/256), dim3(256), 0, stream,
                     Wi, Wh, Wo, WiP, WhcP, WocP, cb, wob);

  hipFuncSetAttribute(reinterpret_cast<const void*>(cw_main),
                      hipFuncAttributeMaxDynamicSharedMemorySize, SMEM_BYTES);

  hipLaunchKernelGGL(cw_main, dim3(BB), dim3(512), SMEM_BYTES, stream,
                     X, WiP, WhcP, WocP, cb, wob, Y, Hout);
}

// Round 3
// 489.370 us; speedup vs baseline: 3.3490x; 3.3490x over previous
//
#include <hip/hip_runtime.h>

// ClockworkRNN on MI355X — v3 (= v2 + igemm block-offset fix).
// prep: pack weights f16.  igemm: I = Wi.x at active timesteps only (MFMA, compressed layout).
// main: 1 WG / batch column; Wh/Wo hot fragments in registers; ctx/octx caching;
//       fdot2 + DPP reductions; lgkmcnt-only barriers.

typedef unsigned int  u32;
typedef unsigned short u16;
typedef _Float16 f16;
typedef f16   f16x2 __attribute__((ext_vector_type(2)));
typedef f16   f16x8 __attribute__((ext_vector_type(8)));
typedef float f32x4 __attribute__((ext_vector_type(4)));

#define TT   512
#define BB   256
#define NI_  128
#define NO_  128

#define WIP_N  32768   // [r][64 pairs]
#define WHCP_N 73728   // per jp: offset 1024*jp*(jp+1), [64*(jp+1) rows][32 pairs]
#define WOCP_N 32768   // per jp: [g][row*4+k][4 pairs]  (4096 u32 per jp, 2048 per g)
#define ICOMP_PER_B 65280  // f16 per batch col:  64 * sum_j(512>>j)

__device__ __forceinline__ u32 pk2(float a, float b){
  f16x2 v; v.x=(f16)a; v.y=(f16)b; return __builtin_bit_cast(u32, v);
}
__device__ __forceinline__ float tanh_fast(float x){
  float e = __expf(2.0f*x);
  return 1.0f - 2.0f/(e + 1.0f);
}
__device__ __forceinline__ float dot2(u32 a, u32 b, float c){
#if __has_builtin(__builtin_amdgcn_fdot2)
  return __builtin_amdgcn_fdot2(__builtin_bit_cast(f16x2,a), __builtin_bit_cast(f16x2,b), c, false);
#else
  f16x2 x = __builtin_bit_cast(f16x2,a), y = __builtin_bit_cast(f16x2,b);
  c = fmaf((float)x.x,(float)y.x,c); c = fmaf((float)x.y,(float)y.y,c); return c;
#endif
}
__device__ __forceinline__ float dot4(uint4 w, uint4 h){
  float a = dot2(w.x,h.x, dot2(w.z,h.z,0.f));
  float q = dot2(w.y,h.y, dot2(w.w,h.w,0.f));
  return a+q;
}
template<int CTRL>
__device__ __forceinline__ float dppadd(float v){
  int x = __builtin_amdgcn_update_dpp(0, __builtin_bit_cast(int,v), CTRL, 0xf, 0xf, true);
  return v + __builtin_bit_cast(float,x);
}
// sum over 8 consecutive lanes (8-aligned groups): quad xor1, quad xor2, half-row mirror (l^7)
__device__ __forceinline__ float red8(float v){ v=dppadd<0xB1>(v); v=dppadd<0x4E>(v); v=dppadd<0x141>(v); return v; }
// sum over quads
__device__ __forceinline__ float red4(float v){ v=dppadd<0xB1>(v); v=dppadd<0x4E>(v); return v; }

__device__ __forceinline__ float f16at(uint4 v, int i){
  const u32 w = (i<2)? v.x : (i<4)? v.y : (i<6)? v.z : v.w;
  const u16 h = (i&1) ? (u16)(w>>16) : (u16)(w & 0xffffu);
  return (float)__builtin_bit_cast(f16, h);
}

// barrier that does NOT drain vmcnt (keeps Y-stores / I-prefetch in flight)
#define BAR() asm volatile("s_waitcnt lgkmcnt(0)\n\ts_barrier" ::: "memory")

// ---------------- prep: pack weights ----------------
__global__ __launch_bounds__(256) void cw_prep(
    const float* __restrict__ Wi, const float* __restrict__ Wh, const float* __restrict__ Wo,
    u32* __restrict__ WiP, u32* __restrict__ WhcP, u32* __restrict__ WocP,
    float* __restrict__ cb, float* __restrict__ wob)
{
  const int NTOT = WIP_N + WHCP_N + WOCP_N + 512 + 128;
  for (int idx = blockIdx.x*blockDim.x + threadIdx.x; idx < NTOT; idx += (int)(gridDim.x*blockDim.x)){
    if (idx < WIP_N){
      int r  = idx >> 6;
      int c2 = idx & 63;
      WiP[idx] = pk2(Wi[r*129 + 2*c2], Wi[r*129 + 2*c2 + 1]);
    } else if (idx < WIP_N + WHCP_N){
      int q = idx - WIP_N;
      int jp = 0;
      while (jp < 7 && q >= 1024*(jp+1)*(jp+2)) ++jp;
      int rem = q - 1024*jp*(jp+1);
      int r   = rem >> 5;
      int c2  = rem & 31;
      WhcP[q] = pk2(Wh[r*513 + 64*jp + 2*c2], Wh[r*513 + 64*jp + 2*c2 + 1]);
    } else if (idx < WIP_N + WHCP_N + WOCP_N){
      int q    = idx - WIP_N - WHCP_N;
      int jp   = q >> 12;
      int rem  = q & 4095;
      int g    = rem >> 11;
      int rem2 = rem & 2047;
      int rowk = rem2 >> 2;
      int e    = rem2 & 3;
      int row  = rowk >> 2;
      int k    = rowk & 3;
      int pair = k*8 + g*4 + e;
      WocP[q] = pk2(Wo[row*513 + 64*jp + 2*pair], Wo[row*513 + 64*jp + 2*pair + 1]);
    } else if (idx < WIP_N + WHCP_N + WOCP_N + 512){
      int r = idx - WIP_N - WHCP_N - WOCP_N;
      cb[r] = Wh[r*513 + 512] + Wi[r*129 + 128];
    } else {
      int o = idx - WIP_N - WHCP_N - WOCP_N - 512;
      wob[o] = Wo[o*513 + 512];
    }
  }
}

// ---------------- igemm: I[b][block j][row][m] = Wi_row . x_{t=m<<j} ----------------
__global__ __launch_bounds__(256) void cw_igemm(
    const float* __restrict__ X, const u32* __restrict__ WiP, f16* __restrict__ Icomp)
{
  const int tid = threadIdx.x;
  const int l = tid & 63, w = tid >> 6;
  const int bid = blockIdx.x;
  const int b = bid / 19, sub = bid % 19;
  int j, m0;
  if      (sub <  8){ j = 0; m0 = sub*64; }
  else if (sub < 12){ j = 1; m0 = (sub-8)*64; }
  else if (sub < 14){ j = 2; m0 = (sub-12)*64; }
  else if (sub ==14){ j = 3; m0 = 0; }
  else              { j = sub-11; m0 = 0; }
  const int Nj = 512 >> j;
  const int mt = m0 + w*16;
  const int la = l & 15, lb = l >> 4;

  int ma = mt + la; if (ma >= Nj) ma = Nj - 1;
  const int t = ma << j;
  const float* Xr = X + ((size_t)t*BB + b)*NI_ + lb*8;
  // FIX v3: block-j row offset (j<<12 u32 = 64 rows * 64 pairs) was missing in v2.
  const u32* wp0 = WiP + (j<<12) + la*64 + lb*4;

  f32x4 a0 = {0.f,0.f,0.f,0.f}, a1 = a0, a2 = a0, a3 = a0;
  #pragma unroll
  for (int ks = 0; ks < 4; ++ks){
    const float4 x0 = *(const float4*)(Xr + ks*32);
    const float4 x1 = *(const float4*)(Xr + ks*32 + 4);
    uint4 au;
    au.x = __builtin_bit_cast(u32, __builtin_amdgcn_cvt_pkrtz(x0.x, x0.y));
    au.y = __builtin_bit_cast(u32, __builtin_amdgcn_cvt_pkrtz(x0.z, x0.w));
    au.z = __builtin_bit_cast(u32, __builtin_amdgcn_cvt_pkrtz(x1.x, x1.y));
    au.w = __builtin_bit_cast(u32, __builtin_amdgcn_cvt_pkrtz(x1.z, x1.w));
    const f16x8 af = __builtin_bit_cast(f16x8, au);
    const u32* wp = wp0 + ks*16;
    a0 = __builtin_amdgcn_mfma_f32_16x16x32_f16(af, __builtin_bit_cast(f16x8, *(const uint4*)(wp       )), a0, 0,0,0);
    a1 = __builtin_amdgcn_mfma_f32_16x16x32_f16(af, __builtin_bit_cast(f16x8, *(const uint4*)(wp + 1024)), a1, 0,0,0);
    a2 = __builtin_amdgcn_mfma_f32_16x16x32_f16(af, __builtin_bit_cast(f16x8, *(const uint4*)(wp + 2048)), a2, 0,0,0);
    a3 = __builtin_amdgcn_mfma_f32_16x16x32_f16(af, __builtin_bit_cast(f16x8, *(const uint4*)(wp + 3072)), a3, 0,0,0);
  }
  const int mb = mt + lb*4;
  if (mb < Nj){
    const size_t offj = 65536 - (65536 >> j);
    f16* base = Icomp + (size_t)b*ICOMP_PER_B + offj + mb;
    uint2 s;
    s.x = __builtin_bit_cast(u32, __builtin_amdgcn_cvt_pkrtz(a0[0], a0[1]));
    s.y = __builtin_bit_cast(u32, __builtin_amdgcn_cvt_pkrtz(a0[2], a0[3]));
    *(uint2*)(base + (size_t)( 0 + la)*Nj) = s;
    s.x = __builtin_bit_cast(u32, __builtin_amdgcn_cvt_pkrtz(a1[0], a1[1]));
    s.y = __builtin_bit_cast(u32, __builtin_amdgcn_cvt_pkrtz(a1[2], a1[3]));
    *(uint2*)(base + (size_t)(16 + la)*Nj) = s;
    s.x = __builtin_bit_cast(u32, __builtin_amdgcn_cvt_pkrtz(a2[0], a2[1]));
    s.y = __builtin_bit_cast(u32, __builtin_amdgcn_cvt_pkrtz(a2[2], a2[3]));
    *(uint2*)(base + (size_t)(32 + la)*Nj) = s;
    s.x = __builtin_bit_cast(u32, __builtin_amdgcn_cvt_pkrtz(a3[0], a3[1]));
    s.y = __builtin_bit_cast(u32, __builtin_amdgcn_cvt_pkrtz(a3[2], a3[3]));
    *(uint2*)(base + (size_t)(48 + la)*Nj) = s;
  }
}

// ---------------- main recurrence ----------------
__device__ __forceinline__ uint4 load_I(const f16* __restrict__ Ib, int wv, int ln, int c){
  uint4 v; v.x = v.y = v.z = v.w = 0u;
  if (wv == 0){
    v = *(const uint4*)(Ib + (size_t)ln*512 + c*8);
  } else if (wv == 1){
    const uint2 u = *(const uint2*)(Ib + 32768 + ln*256 + c*4);
    v.x = u.x; v.y = u.y;
  } else if (wv == 2){
    v.x = *(const u32*)(Ib + 49152 + ln*128 + c*2);
  } else if (wv == 3){
    v.x = *(const u16*)(Ib + 57344 + ln*64 + c);
  } else if (wv == 4){
    if (!(c & 1))  v.x = *(const u16*)(Ib + 61440 + ln*32 + (c>>1));
  } else if (wv == 5){
    if (!(c & 3))  v.x = *(const u16*)(Ib + 63488 + ln*16 + (c>>2));
  } else if (wv == 6){
    if (!(c & 7))  v.x = *(const u16*)(Ib + 64512 + ln*8  + (c>>3));
  } else {
    if (!(c & 15)) v.x = *(const u16*)(Ib + 65024 + ln*4  + (c>>4));
  }
  return v;
}

__device__ __forceinline__ void cpass(uint4 w, uint4 hq, int jp, int row, int k8, float* sctx){
  float v = red8(dot4(w, hq));
  if (k8 == 0) sctx[row*8 + jp] = v;
}
__device__ __forceinline__ void dpassw(uint4 w0, uint4 w1, int jp, int rl4, int k4,
                                       float* soctx, const u32* sHu){
  const uint4 h0 = *(const uint4*)(sHu + jp*32 + k4*8);
  const uint4 h1 = *(const uint4*)(sHu + jp*32 + k4*8 + 4);
  float v = red4(dot4(w0,h0) + dot4(w1,h1));
  if (k4 == 0) soctx[rl4*8 + jp] = v;
}

__global__ __launch_bounds__(512, 2) void cw_main(
    const f16* __restrict__ Icomp,
    const u32* __restrict__ WhcG, const u32* __restrict__ WocG,
    const float* __restrict__ cbg, const float* __restrict__ wobg,
    float* __restrict__ Y, float* __restrict__ Hout)
{
  __shared__ __align__(16) float sctx [512*8];  // [r][q]  (q<block(r) stay 0 => full sum == masked sum)
  __shared__ __align__(16) float soctx[128*8];  // [o][jp]
  __shared__ __align__(16) f16   sH  [512];

  const int tid = (int)threadIdx.x;
  const int b   = (int)blockIdx.x;
  const int wv  = tid >> 6, ln = tid & 63;
  const int rl8 = tid >> 3, k8 = tid & 7;
  const int rl4 = tid >> 2, k4 = tid & 3;
  const u32* sHu = (const u32*)sH;

  // hot weight fragments -> registers (fixed per thread for the whole kernel)
  const uint4 c00 = *(const uint4*)(WhcG +     0 + (  0+rl8)*32 + k8*4);
  const uint4 c10 = *(const uint4*)(WhcG +  2048 + (  0+rl8)*32 + k8*4);
  const uint4 c11 = *(const uint4*)(WhcG +  2048 + ( 64+rl8)*32 + k8*4);
  const uint4 c20 = *(const uint4*)(WhcG +  6144 + (  0+rl8)*32 + k8*4);
  const uint4 c21 = *(const uint4*)(WhcG +  6144 + ( 64+rl8)*32 + k8*4);
  const uint4 c22 = *(const uint4*)(WhcG +  6144 + (128+rl8)*32 + k8*4);
  const uint4 c30 = *(const uint4*)(WhcG + 12288 + (  0+rl8)*32 + k8*4);
  const uint4 c31 = *(const uint4*)(WhcG + 12288 + ( 64+rl8)*32 + k8*4);
  const uint4 c32 = *(const uint4*)(WhcG + 12288 + (128+rl8)*32 + k8*4);
  const uint4 c33 = *(const uint4*)(WhcG + 12288 + (192+rl8)*32 + k8*4);
  const uint4 d00 = *(const uint4*)(WocG +     0 + (rl4*4+k4)*4);
  const uint4 d01 = *(const uint4*)(WocG +  2048 + (rl4*4+k4)*4);
  const uint4 d10 = *(const uint4*)(WocG +  4096 + (rl4*4+k4)*4);
  const uint4 d11 = *(const uint4*)(WocG +  6144 + (rl4*4+k4)*4);
  const uint4 d20 = *(const uint4*)(WocG +  8192 + (rl4*4+k4)*4);
  const uint4 d21 = *(const uint4*)(WocG + 10240 + (rl4*4+k4)*4);
  const uint4 d30 = *(const uint4*)(WocG + 12288 + (rl4*4+k4)*4);
  const uint4 d31 = *(const uint4*)(WocG + 14336 + (rl4*4+k4)*4);
  const float cbreg  = cbg[tid];
  const float wobreg = (wv >= 6) ? wobg[tid-384] : 0.f;
  f16 hreg = (f16)0.f;

  for (int i = tid; i < 4096; i += 512) sctx[i]  = 0.f;
  for (int i = tid; i < 1024; i += 512) soctx[i] = 0.f;
  sH[tid] = (f16)0.f;

  const f16* Ib = Icomp + (size_t)b*ICOMP_PER_B;
  uint4 inxt = load_I(Ib, wv, ln, 0);
  uint4 icur;
  __syncthreads();

#define PHA(S_, NACT_) do{ \
    if (wv < (NACT_)){ \
      float xv; \
      if      (wv == 0) xv = f16at(icur, (S_)); \
      else if (wv == 1) xv = f16at(icur, (S_)>>1); \
      else if (wv == 2) xv = f16at(icur, (S_)>>2); \
      else              xv = f16at(icur, 0); \
      const float4 cA = *(const float4*)(sctx + tid*8); \
      const float4 cB = *(const float4*)(sctx + tid*8 + 4); \
      float z = cbreg + xv + (((cA.x+cA.y)+(cA.z+cA.w)) + ((cB.x+cB.y)+(cB.z+cB.w))); \
      hreg = (f16)tanh_fast(z); \
      sH[tid] = hreg; \
    } \
  }while(0)

#define PHE(T_) do{ \
    if (wv >= 6){ const int o = tid - 384; \
      const float4 sA = *(const float4*)(soctx + o*8); \
      const float4 sB = *(const float4*)(soctx + o*8 + 4); \
      float zy = wobreg + (((sA.x+sA.y)+(sA.z+sA.w)) + ((sB.x+sB.y)+(sB.z+sB.w))); \
      Y[((size_t)(T_)*BB + b)*NO_ + o] = tanh_fast(zy); \
    } \
  }while(0)

#define STEP(S_) do{ \
    const int t_ = tbase + (S_); \
    if ((S_) != 0 || c != 0) PHE(t_ - 1); \
    const int na_ = ((S_) == 0) ? nc : ((((S_)&3)==0) ? 3 : ((((S_)&1)==0) ? 2 : 1)); \
    PHA(S_, na_); \
    BAR(); \
    { \
      const uint4 hq0 = *(const uint4*)(sHu + k8*4); \
      cpass(c00, hq0, 0, rl8, k8, sctx); \
      dpassw(d00, d01, 0, rl4, k4, soctx, sHu); \
      if ((S_) == 0 || na_ >= 2){ \
        const uint4 hq1 = *(const uint4*)(sHu + 32 + k8*4); \
        cpass(c10, hq1, 1, rl8,    k8, sctx); \
        cpass(c11, hq1, 1, rl8+64, k8, sctx); \
        dpassw(d10, d11, 1, rl4, k4, soctx, sHu); \
      } \
      if ((S_) == 0 || na_ >= 3){ \
        const uint4 hq2 = *(const uint4*)(sHu + 64 + k8*4); \
        cpass(c20, hq2, 2, rl8,     k8, sctx); \
        cpass(c21, hq2, 2, rl8+64,  k8, sctx); \
        cpass(c22, hq2, 2, rl8+128, k8, sctx); \
        dpassw(d20, d21, 2, rl4, k4, soctx, sHu); \
      } \
      if ((S_) == 0){ \
        const uint4 hq3 = *(const uint4*)(sHu + 96 + k8*4); \
        cpass(c30, hq3, 3, rl8,     k8, sctx); \
        cpass(c31, hq3, 3, rl8+64,  k8, sctx); \
        cpass(c32, hq3, 3, rl8+128, k8, sctx); \
        cpass(c33, hq3, 3, rl8+192, k8, sctx); \
        dpassw(d30, d31, 3, rl4, k4, soctx, sHu); \
        for (int jp = 4; jp < nc; ++jp){ \
          const uint4 hqd = *(const uint4*)(sHu + jp*32 + k8*4); \
          const u32* Wb = WhcG + ((jp*(jp+1))<<10) + rl8*32 + k8*4; \
          for (int tau = 0; tau <= jp; ++tau) \
            cpass(*(const uint4*)(Wb + tau*2048), hqd, jp, rl8 + tau*64, k8, sctx); \
          const uint4 w0d = *(const uint4*)(WocG + (jp<<12)        + (rl4*4+k4)*4); \
          const uint4 w1d = *(const uint4*)(WocG + (jp<<12) + 2048 + (rl4*4+k4)*4); \
          dpassw(w0d, w1d, jp, rl4, k4, soctx, sHu); \
        } \
      } \
    } \
    BAR(); \
  }while(0)

  for (int c = 0; c < 64; ++c){
    const int tbase = c*8;
    int nc;
    if (c == 0) nc = 8;
    else { nc = 4 + __builtin_ctz(c); if (nc > 8) nc = 8; }
    icur = inxt;
    if (c < 63) inxt = load_I(Ib, wv, ln, c+1);
    STEP(0); STEP(1); STEP(2); STEP(3); STEP(4); STEP(5); STEP(6); STEP(7);
  }
  PHE(511);
  Hout[(size_t)tid*BB + b] = (float)hreg;

#undef PHA
#undef PHE
#undef STEP
}

extern "C" void kernel_launch(void* const* d_in, const int* in_sizes, int n_in,
                              void* d_out, int out_size, void* d_ws, size_t ws_size,
                              hipStream_t stream)
{
  const float* X  = (const float*)d_in[0];
  const float* Wi = (const float*)d_in[1];
  const float* Wh = (const float*)d_in[2];
  const float* Wo = (const float*)d_in[3];

  u32*   WiP   = (u32*)d_ws;
  u32*   WhcP  = WiP  + WIP_N;
  u32*   WocP  = WhcP + WHCP_N;
  float* cb    = (float*)(WocP + WOCP_N);
  float* wob   = cb + 512;
  f16*   Icomp = (f16*)(wob + 128);

  float* Y    = (float*)d_out;
  float* Hout = Y + (size_t)TT*BB*NO_;

  const int prep_n = WIP_N + WHCP_N + WOCP_N + 512 + 128;
  hipLaunchKernelGGL(cw_prep, dim3((prep_n + 255)/256), dim3(256), 0, stream,
                     Wi, Wh, Wo, WiP, WhcP, WocP, cb, wob);

  hipLaunchKernelGGL(cw_igemm, dim3(256*19), dim3(256), 0, stream,
                     X, WiP, Icomp);

  hipLaunchKernelGGL(cw_main, dim3(BB), dim3(512), 0, stream,
                     Icomp, WhcP, WocP, cb, wob, Y, Hout);
}

// Round 4
// 458.529 us; speedup vs baseline: 3.5743x; 1.0673x over previous
//
#include <hip/hip_runtime.h>

// ClockworkRNN on MI355X — v4.
// prep:   pack weights f16 (Wi for igemm; Wh hot/reg + cold/LDS-swizzled; Wo row-major; biases).
// igemm:  I = Wi.x at active timesteps only (MFMA, compressed [b][j][r][m]).  (validated in v3)
// serial: 256 WGs x 512 thr; wave j owns block j; ctx in registers; row-per-lane GEMV;
//         1 lgkm-only barrier/step; writes compressed trajectory Hcomp[b][j][m][r] + Hout.
// ygemm:  Y = tanh(Wo.H + b) as dense MFMA GEMM gathering B-frags from Hcomp (m = t>>j).

typedef unsigned int  u32;
typedef unsigned short u16;
typedef _Float16 f16;
typedef f16   f16x2 __attribute__((ext_vector_type(2)));
typedef f16   f16x8 __attribute__((ext_vector_type(8)));
typedef float f32x4 __attribute__((ext_vector_type(4)));

#define TT   512
#define BB   256
#define NI_  128
#define NO_  128

// ws layout (u32 units)
#define WIP_N   32768   // Wi packed [r][64 pairs]
#define WHRP_N  49152   // 24 slots (j*3+dq, q=j+dq) x [64 r][32 pairs]
#define WHLP_N  30720   // 15 cold slots x [64 r][8 chunks swizzled][4 pairs]
#define WOA_N   32768   // Wo packed [o][256 pairs]
#define ICOMP_PER_B 65280   // f16 per column: 64 * sum_j (512>>j)

#define SERIAL_LDS (30720*4 + 2048)   // 124928 B

__device__ __forceinline__ u32 pk2(float a, float b){
  f16x2 v; v.x=(f16)a; v.y=(f16)b; return __builtin_bit_cast(u32, v);
}
__device__ __forceinline__ float tanh_fast(float x){
  float e = __expf(2.0f*x);
  return 1.0f - 2.0f/(e + 1.0f);
}
__device__ __forceinline__ float dot2(u32 a, u32 b, float c){
#if __has_builtin(__builtin_amdgcn_fdot2)
  return __builtin_amdgcn_fdot2(__builtin_bit_cast(f16x2,a), __builtin_bit_cast(f16x2,b), c, false);
#else
  f16x2 x = __builtin_bit_cast(f16x2,a), y = __builtin_bit_cast(f16x2,b);
  c = fmaf((float)x.x,(float)y.x,c); c = fmaf((float)x.y,(float)y.y,c); return c;
#endif
}
__device__ __forceinline__ float f16at_rt(uint4 v, int i){
  u32 w = (i&4) ? ((i&2)? v.w : v.z) : ((i&2)? v.y : v.x);
  w = (i&1) ? (w>>16) : (w & 0xffffu);
  return (float)__builtin_bit_cast(f16, (u16)w);
}

// barrier that does NOT drain vmcnt (keeps global stores/prefetch in flight)
#define BAR() asm volatile("s_waitcnt lgkmcnt(0)\n\ts_barrier" ::: "memory")

// ---------------- prep ----------------
__global__ __launch_bounds__(256) void cw_prep(
    const float* __restrict__ Wi, const float* __restrict__ Wh, const float* __restrict__ Wo,
    u32* __restrict__ WiP, u32* __restrict__ WhrP, u32* __restrict__ WhlP, u32* __restrict__ WoAu,
    float* __restrict__ cb, float* __restrict__ wob)
{
  const int NTOT = WIP_N + WHRP_N + WHLP_N + WOA_N + 512 + 128;
  for (int idx = blockIdx.x*blockDim.x + threadIdx.x; idx < NTOT; idx += (int)(gridDim.x*blockDim.x)){
    if (idx < WIP_N){
      int r  = idx >> 6;
      int c2 = idx & 63;
      WiP[idx] = pk2(Wi[r*129 + 2*c2], Wi[r*129 + 2*c2 + 1]);
    } else if (idx < WIP_N + WHRP_N){
      int q32 = idx - WIP_N;
      int slot = q32 >> 11, rr = (q32 >> 5) & 63, c4 = q32 & 31;
      int jj = slot / 3, dq = slot % 3, qq = jj + dq;
      u32 v = 0u;
      if (qq <= 7){
        int row = 64*jj + rr;
        v = pk2(Wh[row*513 + 64*qq + 2*c4], Wh[row*513 + 64*qq + 2*c4 + 1]);
      }
      WhrP[q32] = v;
    } else if (idx < WIP_N + WHRP_N + WHLP_N){
      int q32 = idx - WIP_N - WHRP_N;
      int slot = q32 >> 11, rr = (q32 >> 5) & 63, pos = (q32 >> 2) & 7, e = q32 & 3;
      int jj, qq;
      if      (slot <  5){ jj = 0; qq = slot + 3; }
      else if (slot <  9){ jj = 1; qq = slot - 1; }
      else if (slot < 12){ jj = 2; qq = slot - 4; }
      else if (slot < 14){ jj = 3; qq = slot - 6; }
      else               { jj = 4; qq = 7; }
      int i  = pos ^ (rr & 7);          // swizzled chunk placement
      int cp = i*4 + e;
      int row = 64*jj + rr;
      WhlP[q32] = pk2(Wh[row*513 + 64*qq + 2*cp], Wh[row*513 + 64*qq + 2*cp + 1]);
    } else if (idx < WIP_N + WHRP_N + WHLP_N + WOA_N){
      int q32 = idx - WIP_N - WHRP_N - WHLP_N;
      int o = q32 >> 8, kp = q32 & 255;
      WoAu[q32] = pk2(Wo[o*513 + 2*kp], Wo[o*513 + 2*kp + 1]);
    } else if (idx < WIP_N + WHRP_N + WHLP_N + WOA_N + 512){
      int r = idx - WIP_N - WHRP_N - WHLP_N - WOA_N;
      cb[r] = Wh[r*513 + 512] + Wi[r*129 + 128];
    } else {
      int o = idx - WIP_N - WHRP_N - WHLP_N - WOA_N - 512;
      wob[o] = Wo[o*513 + 512];
    }
  }
}

// ---------------- igemm (unchanged from v3, validated) ----------------
__global__ __launch_bounds__(256) void cw_igemm(
    const float* __restrict__ X, const u32* __restrict__ WiP, f16* __restrict__ Icomp)
{
  const int tid = threadIdx.x;
  const int l = tid & 63, w = tid >> 6;
  const int bid = blockIdx.x;
  const int b = bid / 19, sub = bid % 19;
  int j, m0;
  if      (sub <  8){ j = 0; m0 = sub*64; }
  else if (sub < 12){ j = 1; m0 = (sub-8)*64; }
  else if (sub < 14){ j = 2; m0 = (sub-12)*64; }
  else if (sub ==14){ j = 3; m0 = 0; }
  else              { j = sub-11; m0 = 0; }
  const int Nj = 512 >> j;
  const int mt = m0 + w*16;
  const int la = l & 15, lb = l >> 4;

  int ma = mt + la; if (ma >= Nj) ma = Nj - 1;
  const int t = ma << j;
  const float* Xr = X + ((size_t)t*BB + b)*NI_ + lb*8;
  const u32* wp0 = WiP + (j<<12) + la*64 + lb*4;

  f32x4 a0 = {0.f,0.f,0.f,0.f}, a1 = a0, a2 = a0, a3 = a0;
  #pragma unroll
  for (int ks = 0; ks < 4; ++ks){
    const float4 x0 = *(const float4*)(Xr + ks*32);
    const float4 x1 = *(const float4*)(Xr + ks*32 + 4);
    uint4 au;
    au.x = __builtin_bit_cast(u32, __builtin_amdgcn_cvt_pkrtz(x0.x, x0.y));
    au.y = __builtin_bit_cast(u32, __builtin_amdgcn_cvt_pkrtz(x0.z, x0.w));
    au.z = __builtin_bit_cast(u32, __builtin_amdgcn_cvt_pkrtz(x1.x, x1.y));
    au.w = __builtin_bit_cast(u32, __builtin_amdgcn_cvt_pkrtz(x1.z, x1.w));
    const f16x8 af = __builtin_bit_cast(f16x8, au);
    const u32* wp = wp0 + ks*16;
    a0 = __builtin_amdgcn_mfma_f32_16x16x32_f16(af, __builtin_bit_cast(f16x8, *(const uint4*)(wp       )), a0, 0,0,0);
    a1 = __builtin_amdgcn_mfma_f32_16x16x32_f16(af, __builtin_bit_cast(f16x8, *(const uint4*)(wp + 1024)), a1, 0,0,0);
    a2 = __builtin_amdgcn_mfma_f32_16x16x32_f16(af, __builtin_bit_cast(f16x8, *(const uint4*)(wp + 2048)), a2, 0,0,0);
    a3 = __builtin_amdgcn_mfma_f32_16x16x32_f16(af, __builtin_bit_cast(f16x8, *(const uint4*)(wp + 3072)), a3, 0,0,0);
  }
  const int mb = mt + lb*4;
  if (mb < Nj){
    const size_t offj = 65536 - (65536 >> j);
    f16* base = Icomp + (size_t)b*ICOMP_PER_B + offj + mb;
    uint2 s;
    s.x = __builtin_bit_cast(u32, __builtin_amdgcn_cvt_pkrtz(a0[0], a0[1]));
    s.y = __builtin_bit_cast(u32, __builtin_amdgcn_cvt_pkrtz(a0[2], a0[3]));
    *(uint2*)(base + (size_t)( 0 + la)*Nj) = s;
    s.x = __builtin_bit_cast(u32, __builtin_amdgcn_cvt_pkrtz(a1[0], a1[1]));
    s.y = __builtin_bit_cast(u32, __builtin_amdgcn_cvt_pkrtz(a1[2], a1[3]));
    *(uint2*)(base + (size_t)(16 + la)*Nj) = s;
    s.x = __builtin_bit_cast(u32, __builtin_amdgcn_cvt_pkrtz(a2[0], a2[1]));
    s.y = __builtin_bit_cast(u32, __builtin_amdgcn_cvt_pkrtz(a2[2], a2[3]));
    *(uint2*)(base + (size_t)(32 + la)*Nj) = s;
    s.x = __builtin_bit_cast(u32, __builtin_amdgcn_cvt_pkrtz(a3[0], a3[1]));
    s.y = __builtin_bit_cast(u32, __builtin_amdgcn_cvt_pkrtz(a3[2], a3[3]));
    *(uint2*)(base + (size_t)(48 + la)*Nj) = s;
  }
}

// ---------------- serial recurrence ----------------
__device__ __forceinline__ float gemv8(const uint4 (&W)[8], const u32* hq){
  float a0 = 0.f, a1 = 0.f;
  #pragma unroll
  for (int i = 0; i < 8; ++i){
    const uint4 hv = *(const uint4*)(hq + i*4);
    a0 = dot2(W[i].x, hv.x, a0); a1 = dot2(W[i].y, hv.y, a1);
    a0 = dot2(W[i].z, hv.z, a0); a1 = dot2(W[i].w, hv.w, a1);
  }
  return a0 + a1;
}
__device__ __forceinline__ float gemv_lds(const u32* wp, const u32* hq, int rx){
  float a0 = 0.f, a1 = 0.f;
  #pragma unroll
  for (int i = 0; i < 8; ++i){
    const uint4 w  = *(const uint4*)(wp + ((i ^ rx) << 2));
    const uint4 hv = *(const uint4*)(hq + i*4);
    a0 = dot2(w.x, hv.x, a0); a1 = dot2(w.y, hv.y, a1);
    a0 = dot2(w.z, hv.z, a0); a1 = dot2(w.w, hv.w, a1);
  }
  return a0 + a1;
}

template<int J>
__device__ void run_wave(const f16* __restrict__ Ib, const u32* __restrict__ whr,
                         const u32* __restrict__ sWc, u32* hbu, u16* hbs,
                         f16* __restrict__ Hc, float* __restrict__ Hout,
                         float cbv, int r, int b)
{
  constexpr int NJ = 512 >> J;
  constexpr int NB = 8 - J;
  uint4 W0[8], W1[8], W2[8];
  {
    const u32* w0 = whr + (J*3)*2048 + r*32;
    #pragma unroll
    for (int i = 0; i < 8; ++i) W0[i] = *(const uint4*)(w0 + i*4);
    if constexpr (NB > 1){
      #pragma unroll
      for (int i = 0; i < 8; ++i) W1[i] = *(const uint4*)(w0 + 2048 + i*4);
    }
    if constexpr (NB > 2){
      #pragma unroll
      for (int i = 0; i < 8; ++i) W2[i] = *(const uint4*)(w0 + 4096 + i*4);
    }
  }
  float ctx[8];
  #pragma unroll
  for (int q = 0; q < 8; ++q) ctx[q] = 0.f;

  uint4 icur = {0,0,0,0}, inxt = {0,0,0,0};
  if constexpr (NJ >= 8) icur = *(const uint4*)(Ib);
  else { const uint2 u2 = *(const uint2*)(Ib); icur.x = u2.x; icur.y = u2.y; }

  int m = 0;
  float h = 0.f; u16 hbits = 0;
  { // t = 0: all blocks update from H(-1)=0 (ctx all zero)
    float z = cbv + f16at_rt(icur, 0);
    h = tanh_fast(z);
    const f16 h16 = (f16)h; hbits = __builtin_bit_cast(u16, h16);
    Hc[r] = h16;
    m = 1;
    if constexpr (NJ > 8) inxt = *(const uint4*)(Ib + 8);
    hbs[J*64 + r] = hbits;            // hb[0]
  }
  BAR();

  for (int t = 1; t < 512; ++t){
    const int A0 = __builtin_ctz((unsigned)(t-1) | 256u);   // t-1==0 -> 8 -> all
    const int A = (A0 > 7) ? 7 : A0;
    const u32* hq0 = hbu + (((t-1)&1) << 8);

    if (J + 0 <= A) ctx[J+0] = gemv8(W0, hq0 + (J+0)*32);
    if constexpr (NB > 1){ if (J + 1 <= A) ctx[J+1] = gemv8(W1, hq0 + (J+1)*32); }
    if constexpr (NB > 2){ if (J + 2 <= A) ctx[J+2] = gemv8(W2, hq0 + (J+2)*32); }
    if constexpr (J <= 4){
      constexpr int CB = (J==0) ? 0 : (J==1) ? 5 : (J==2) ? 9 : (J==3) ? 12 : 14;
      #pragma unroll
      for (int dq = 3; dq < NB; ++dq){
        const int q = J + dq;
        if (q <= A) ctx[q] = gemv_lds(sWc + (CB + dq - 3)*2048 + r*32, hq0 + q*32, r & 7);
      }
    }

    if ((t & ((1 << J) - 1)) == 0){
      const int e = m & 7;
      if constexpr (NJ > 8){ if (e == 0 && m + 8 < NJ) inxt = *(const uint4*)(Ib + m + 8); }
      float z = cbv + f16at_rt(icur, e);
      #pragma unroll
      for (int q = J; q < 8; ++q) z += ctx[q];
      h = tanh_fast(z);
      const f16 h16 = (f16)h; hbits = __builtin_bit_cast(u16, h16);
      Hc[m*64 + r] = h16;
      if constexpr (NJ > 8){ if (e == 7) icur = inxt; }
      ++m;
    }
    hbs[((t&1) << 9) + J*64 + r] = hbits;   // current state, every step
    BAR();
  }
  Hout[(J*64 + r)*BB + b] = h;
}

__global__ __launch_bounds__(512) void cw_serial(
    const f16* __restrict__ Icomp, const u32* __restrict__ WhrP, const u32* __restrict__ WhlP,
    const float* __restrict__ cbg, f16* __restrict__ Hcomp, float* __restrict__ Hout)
{
  extern __shared__ u32 smem[];
  u32* sWc = smem;             // 30720 u32
  u32* hbu = smem + 30720;     // 512 u32 (2 x 512 f16)
  u16* hbs = (u16*)hbu;

  const int tid = (int)threadIdx.x;
  const int b   = (int)blockIdx.x;
  const int j   = tid >> 6, r = tid & 63;

  for (int i = tid; i < 30720; i += 512) sWc[i] = WhlP[i];

  const float cbv = cbg[tid];
  const int offh  = (1024 - (1024 >> j)) << 6;
  const f16* Ib = Icomp + (size_t)b*ICOMP_PER_B + offh + r*(512 >> j);
  f16* Hc = Hcomp + (size_t)b*ICOMP_PER_B + offh;

  switch (j){
    case 0: run_wave<0>(Ib, WhrP, sWc, hbu, hbs, Hc, Hout, cbv, r, b); break;
    case 1: run_wave<1>(Ib, WhrP, sWc, hbu, hbs, Hc, Hout, cbv, r, b); break;
    case 2: run_wave<2>(Ib, WhrP, sWc, hbu, hbs, Hc, Hout, cbv, r, b); break;
    case 3: run_wave<3>(Ib, WhrP, sWc, hbu, hbs, Hc, Hout, cbv, r, b); break;
    case 4: run_wave<4>(Ib, WhrP, sWc, hbu, hbs, Hc, Hout, cbv, r, b); break;
    case 5: run_wave<5>(Ib, WhrP, sWc, hbu, hbs, Hc, Hout, cbv, r, b); break;
    case 6: run_wave<6>(Ib, WhrP, sWc, hbu, hbs, Hc, Hout, cbv, r, b); break;
    default: run_wave<7>(Ib, WhrP, sWc, hbu, hbs, Hc, Hout, cbv, r, b); break;
  }
}

// ---------------- ygemm: Y = tanh(Wo.H + b), B-frags gathered from Hcomp ----------------
__global__ __launch_bounds__(512, 2) void cw_ygemm(
    const f16* __restrict__ Hcomp, const u32* __restrict__ WoAu,
    const float* __restrict__ wobg, float* __restrict__ Y)
{
  const int tid = (int)threadIdx.x;
  const int w = tid >> 6, l = tid & 63;
  const int la = l & 15, lb = l >> 4;
  const int b0 = (int)blockIdx.x * 16;
  const int t0 = (int)blockIdx.y * 16;
  const int o0 = w * 16;

  uint4 A[16];
  {
    const u32* ap = WoAu + (o0 + la)*256 + lb*4;
    #pragma unroll
    for (int ks = 0; ks < 16; ++ks) A[ks] = *(const uint4*)(ap + ks*16);
  }
  const float4 wv = *(const float4*)(wobg + o0 + lb*4);
  const int bl = b0 + la;
  const f16* Hb = Hcomp + (size_t)bl * ICOMP_PER_B + lb*8;

  for (int tt = 0; tt < 16; ++tt){
    const int t = t0 + tt;
    f32x4 ac = {0.f, 0.f, 0.f, 0.f};
    #pragma unroll
    for (int ks = 0; ks < 16; ++ks){
      const int jb  = ks >> 1;
      const int off = ((1024 - (1024 >> jb)) << 6) + ((t >> jb) << 6) + ((ks & 1) << 5);
      const uint4 Bf = *(const uint4*)(Hb + off);
      ac = __builtin_amdgcn_mfma_f32_16x16x32_f16(
             __builtin_bit_cast(f16x8, A[ks]), __builtin_bit_cast(f16x8, Bf), ac, 0,0,0);
    }
    float4 yv;
    yv.x = tanh_fast(ac[0] + wv.x);
    yv.y = tanh_fast(ac[1] + wv.y);
    yv.z = tanh_fast(ac[2] + wv.z);
    yv.w = tanh_fast(ac[3] + wv.w);
    *(float4*)(Y + ((size_t)t*BB + bl)*NO_ + o0 + lb*4) = yv;
  }
}

extern "C" void kernel_launch(void* const* d_in, const int* in_sizes, int n_in,
                              void* d_out, int out_size, void* d_ws, size_t ws_size,
                              hipStream_t stream)
{
  const float* X  = (const float*)d_in[0];
  const float* Wi = (const float*)d_in[1];
  const float* Wh = (const float*)d_in[2];
  const float* Wo = (const float*)d_in[3];

  u32*   WiP  = (u32*)d_ws;
  u32*   WhrP = WiP  + WIP_N;
  u32*   WhlP = WhrP + WHRP_N;
  u32*   WoAu = WhlP + WHLP_N;
  float* cb   = (float*)(WoAu + WOA_N);
  float* wob  = cb + 512;
  f16*   Icomp = (f16*)(wob + 128);
  f16*   Hcomp = Icomp + (size_t)BB * ICOMP_PER_B;

  float* Y    = (float*)d_out;
  float* Hout = Y + (size_t)TT*BB*NO_;

  const int prep_n = WIP_N + WHRP_N + WHLP_N + WOA_N + 512 + 128;
  hipLaunchKernelGGL(cw_prep, dim3((prep_n + 255)/256), dim3(256), 0, stream,
                     Wi, Wh, Wo, WiP, WhrP, WhlP, WoAu, cb, wob);

  hipLaunchKernelGGL(cw_igemm, dim3(256*19), dim3(256), 0, stream, X, WiP, Icomp);

  hipFuncSetAttribute(reinterpret_cast<const void*>(cw_serial),
                      hipFuncAttributeMaxDynamicSharedMemorySize, SERIAL_LDS);
  hipLaunchKernelGGL(cw_serial, dim3(BB), dim3(512), SERIAL_LDS, stream,
                     Icomp, WhrP, WhlP, cb, Hcomp, Hout);

  hipLaunchKernelGGL(cw_ygemm, dim3(16, 32), dim3(512), 0, stream,
                     Hcomp, WoAu, wob, Y);
}

// Round 5
// 414.721 us; speedup vs baseline: 3.9518x; 1.1056x over previous
//
#include <hip/hip_runtime.h>

// ClockworkRNN on MI355X — v5 (= v4 with ygemm rewritten for coalesced dataflow).
// prep:   pack weights f16 (unchanged, validated).
// igemm:  I = Wi.x at active timesteps only (unchanged, validated).
// serial: wave-per-block recurrence (unchanged, validated; 280us — next target).
// ygemm2: Y = tanh(Wo.H + b); one batch column per WG, time on the B-column axis:
//         B-frag loads stride 128B / broadcast (L1-friendly), float4 Y stores.

typedef unsigned int  u32;
typedef unsigned short u16;
typedef _Float16 f16;
typedef f16   f16x2 __attribute__((ext_vector_type(2)));
typedef f16   f16x8 __attribute__((ext_vector_type(8)));
typedef float f32x4 __attribute__((ext_vector_type(4)));

#define TT   512
#define BB   256
#define NI_  128
#define NO_  128

// ws layout (u32 units)
#define WIP_N   32768   // Wi packed [r][64 pairs]
#define WHRP_N  49152   // 24 slots (j*3+dq, q=j+dq) x [64 r][32 pairs]
#define WHLP_N  30720   // 15 cold slots x [64 r][8 chunks swizzled][4 pairs]
#define WOA_N   32768   // Wo packed [o][256 pairs]
#define ICOMP_PER_B 65280   // f16 per column: 64 * sum_j (512>>j)

#define SERIAL_LDS (30720*4 + 2048)   // 124928 B

__device__ __forceinline__ u32 pk2(float a, float b){
  f16x2 v; v.x=(f16)a; v.y=(f16)b; return __builtin_bit_cast(u32, v);
}
__device__ __forceinline__ float tanh_fast(float x){
  float e = __expf(2.0f*x);
  return 1.0f - 2.0f/(e + 1.0f);
}
__device__ __forceinline__ float dot2(u32 a, u32 b, float c){
#if __has_builtin(__builtin_amdgcn_fdot2)
  return __builtin_amdgcn_fdot2(__builtin_bit_cast(f16x2,a), __builtin_bit_cast(f16x2,b), c, false);
#else
  f16x2 x = __builtin_bit_cast(f16x2,a), y = __builtin_bit_cast(f16x2,b);
  c = fmaf((float)x.x,(float)y.x,c); c = fmaf((float)x.y,(float)y.y,c); return c;
#endif
}
__device__ __forceinline__ float f16at_rt(uint4 v, int i){
  u32 w = (i&4) ? ((i&2)? v.w : v.z) : ((i&2)? v.y : v.x);
  w = (i&1) ? (w>>16) : (w & 0xffffu);
  return (float)__builtin_bit_cast(f16, (u16)w);
}

// barrier that does NOT drain vmcnt (keeps global stores/prefetch in flight)
#define BAR() asm volatile("s_waitcnt lgkmcnt(0)\n\ts_barrier" ::: "memory")

// ---------------- prep ----------------
__global__ __launch_bounds__(256) void cw_prep(
    const float* __restrict__ Wi, const float* __restrict__ Wh, const float* __restrict__ Wo,
    u32* __restrict__ WiP, u32* __restrict__ WhrP, u32* __restrict__ WhlP, u32* __restrict__ WoAu,
    float* __restrict__ cb, float* __restrict__ wob)
{
  const int NTOT = WIP_N + WHRP_N + WHLP_N + WOA_N + 512 + 128;
  for (int idx = blockIdx.x*blockDim.x + threadIdx.x; idx < NTOT; idx += (int)(gridDim.x*blockDim.x)){
    if (idx < WIP_N){
      int r  = idx >> 6;
      int c2 = idx & 63;
      WiP[idx] = pk2(Wi[r*129 + 2*c2], Wi[r*129 + 2*c2 + 1]);
    } else if (idx < WIP_N + WHRP_N){
      int q32 = idx - WIP_N;
      int slot = q32 >> 11, rr = (q32 >> 5) & 63, c4 = q32 & 31;
      int jj = slot / 3, dq = slot % 3, qq = jj + dq;
      u32 v = 0u;
      if (qq <= 7){
        int row = 64*jj + rr;
        v = pk2(Wh[row*513 + 64*qq + 2*c4], Wh[row*513 + 64*qq + 2*c4 + 1]);
      }
      WhrP[q32] = v;
    } else if (idx < WIP_N + WHRP_N + WHLP_N){
      int q32 = idx - WIP_N - WHRP_N;
      int slot = q32 >> 11, rr = (q32 >> 5) & 63, pos = (q32 >> 2) & 7, e = q32 & 3;
      int jj, qq;
      if      (slot <  5){ jj = 0; qq = slot + 3; }
      else if (slot <  9){ jj = 1; qq = slot - 1; }
      else if (slot < 12){ jj = 2; qq = slot - 4; }
      else if (slot < 14){ jj = 3; qq = slot - 6; }
      else               { jj = 4; qq = 7; }
      int i  = pos ^ (rr & 7);          // swizzled chunk placement
      int cp = i*4 + e;
      int row = 64*jj + rr;
      WhlP[q32] = pk2(Wh[row*513 + 64*qq + 2*cp], Wh[row*513 + 64*qq + 2*cp + 1]);
    } else if (idx < WIP_N + WHRP_N + WHLP_N + WOA_N){
      int q32 = idx - WIP_N - WHRP_N - WHLP_N;
      int o = q32 >> 8, kp = q32 & 255;
      WoAu[q32] = pk2(Wo[o*513 + 2*kp], Wo[o*513 + 2*kp + 1]);
    } else if (idx < WIP_N + WHRP_N + WHLP_N + WOA_N + 512){
      int r = idx - WIP_N - WHRP_N - WHLP_N - WOA_N;
      cb[r] = Wh[r*513 + 512] + Wi[r*129 + 128];
    } else {
      int o = idx - WIP_N - WHRP_N - WHLP_N - WOA_N - 512;
      wob[o] = Wo[o*513 + 512];
    }
  }
}

// ---------------- igemm (unchanged, validated) ----------------
__global__ __launch_bounds__(256) void cw_igemm(
    const float* __restrict__ X, const u32* __restrict__ WiP, f16* __restrict__ Icomp)
{
  const int tid = threadIdx.x;
  const int l = tid & 63, w = tid >> 6;
  const int bid = blockIdx.x;
  const int b = bid / 19, sub = bid % 19;
  int j, m0;
  if      (sub <  8){ j = 0; m0 = sub*64; }
  else if (sub < 12){ j = 1; m0 = (sub-8)*64; }
  else if (sub < 14){ j = 2; m0 = (sub-12)*64; }
  else if (sub ==14){ j = 3; m0 = 0; }
  else              { j = sub-11; m0 = 0; }
  const int Nj = 512 >> j;
  const int mt = m0 + w*16;
  const int la = l & 15, lb = l >> 4;

  int ma = mt + la; if (ma >= Nj) ma = Nj - 1;
  const int t = ma << j;
  const float* Xr = X + ((size_t)t*BB + b)*NI_ + lb*8;
  const u32* wp0 = WiP + (j<<12) + la*64 + lb*4;

  f32x4 a0 = {0.f,0.f,0.f,0.f}, a1 = a0, a2 = a0, a3 = a0;
  #pragma unroll
  for (int ks = 0; ks < 4; ++ks){
    const float4 x0 = *(const float4*)(Xr + ks*32);
    const float4 x1 = *(const float4*)(Xr + ks*32 + 4);
    uint4 au;
    au.x = __builtin_bit_cast(u32, __builtin_amdgcn_cvt_pkrtz(x0.x, x0.y));
    au.y = __builtin_bit_cast(u32, __builtin_amdgcn_cvt_pkrtz(x0.z, x0.w));
    au.z = __builtin_bit_cast(u32, __builtin_amdgcn_cvt_pkrtz(x1.x, x1.y));
    au.w = __builtin_bit_cast(u32, __builtin_amdgcn_cvt_pkrtz(x1.z, x1.w));
    const f16x8 af = __builtin_bit_cast(f16x8, au);
    const u32* wp = wp0 + ks*16;
    a0 = __builtin_amdgcn_mfma_f32_16x16x32_f16(af, __builtin_bit_cast(f16x8, *(const uint4*)(wp       )), a0, 0,0,0);
    a1 = __builtin_amdgcn_mfma_f32_16x16x32_f16(af, __builtin_bit_cast(f16x8, *(const uint4*)(wp + 1024)), a1, 0,0,0);
    a2 = __builtin_amdgcn_mfma_f32_16x16x32_f16(af, __builtin_bit_cast(f16x8, *(const uint4*)(wp + 2048)), a2, 0,0,0);
    a3 = __builtin_amdgcn_mfma_f32_16x16x32_f16(af, __builtin_bit_cast(f16x8, *(const uint4*)(wp + 3072)), a3, 0,0,0);
  }
  const int mb = mt + lb*4;
  if (mb < Nj){
    const size_t offj = 65536 - (65536 >> j);
    f16* base = Icomp + (size_t)b*ICOMP_PER_B + offj + mb;
    uint2 s;
    s.x = __builtin_bit_cast(u32, __builtin_amdgcn_cvt_pkrtz(a0[0], a0[1]));
    s.y = __builtin_bit_cast(u32, __builtin_amdgcn_cvt_pkrtz(a0[2], a0[3]));
    *(uint2*)(base + (size_t)( 0 + la)*Nj) = s;
    s.x = __builtin_bit_cast(u32, __builtin_amdgcn_cvt_pkrtz(a1[0], a1[1]));
    s.y = __builtin_bit_cast(u32, __builtin_amdgcn_cvt_pkrtz(a1[2], a1[3]));
    *(uint2*)(base + (size_t)(16 + la)*Nj) = s;
    s.x = __builtin_bit_cast(u32, __builtin_amdgcn_cvt_pkrtz(a2[0], a2[1]));
    s.y = __builtin_bit_cast(u32, __builtin_amdgcn_cvt_pkrtz(a2[2], a2[3]));
    *(uint2*)(base + (size_t)(32 + la)*Nj) = s;
    s.x = __builtin_bit_cast(u32, __builtin_amdgcn_cvt_pkrtz(a3[0], a3[1]));
    s.y = __builtin_bit_cast(u32, __builtin_amdgcn_cvt_pkrtz(a3[2], a3[3]));
    *(uint2*)(base + (size_t)(48 + la)*Nj) = s;
  }
}

// ---------------- serial recurrence (unchanged, validated) ----------------
__device__ __forceinline__ float gemv8(const uint4 (&W)[8], const u32* hq){
  float a0 = 0.f, a1 = 0.f;
  #pragma unroll
  for (int i = 0; i < 8; ++i){
    const uint4 hv = *(const uint4*)(hq + i*4);
    a0 = dot2(W[i].x, hv.x, a0); a1 = dot2(W[i].y, hv.y, a1);
    a0 = dot2(W[i].z, hv.z, a0); a1 = dot2(W[i].w, hv.w, a1);
  }
  return a0 + a1;
}
__device__ __forceinline__ float gemv_lds(const u32* wp, const u32* hq, int rx){
  float a0 = 0.f, a1 = 0.f;
  #pragma unroll
  for (int i = 0; i < 8; ++i){
    const uint4 w  = *(const uint4*)(wp + ((i ^ rx) << 2));
    const uint4 hv = *(const uint4*)(hq + i*4);
    a0 = dot2(w.x, hv.x, a0); a1 = dot2(w.y, hv.y, a1);
    a0 = dot2(w.z, hv.z, a0); a1 = dot2(w.w, hv.w, a1);
  }
  return a0 + a1;
}

template<int J>
__device__ void run_wave(const f16* __restrict__ Ib, const u32* __restrict__ whr,
                         const u32* __restrict__ sWc, u32* hbu, u16* hbs,
                         f16* __restrict__ Hc, float* __restrict__ Hout,
                         float cbv, int r, int b)
{
  constexpr int NJ = 512 >> J;
  constexpr int NB = 8 - J;
  uint4 W0[8], W1[8], W2[8];
  {
    const u32* w0 = whr + (J*3)*2048 + r*32;
    #pragma unroll
    for (int i = 0; i < 8; ++i) W0[i] = *(const uint4*)(w0 + i*4);
    if constexpr (NB > 1){
      #pragma unroll
      for (int i = 0; i < 8; ++i) W1[i] = *(const uint4*)(w0 + 2048 + i*4);
    }
    if constexpr (NB > 2){
      #pragma unroll
      for (int i = 0; i < 8; ++i) W2[i] = *(const uint4*)(w0 + 4096 + i*4);
    }
  }
  float ctx[8];
  #pragma unroll
  for (int q = 0; q < 8; ++q) ctx[q] = 0.f;

  uint4 icur = {0,0,0,0}, inxt = {0,0,0,0};
  if constexpr (NJ >= 8) icur = *(const uint4*)(Ib);
  else { const uint2 u2 = *(const uint2*)(Ib); icur.x = u2.x; icur.y = u2.y; }

  int m = 0;
  float h = 0.f; u16 hbits = 0;
  { // t = 0: all blocks update from H(-1)=0 (ctx all zero)
    float z = cbv + f16at_rt(icur, 0);
    h = tanh_fast(z);
    const f16 h16 = (f16)h; hbits = __builtin_bit_cast(u16, h16);
    Hc[r] = h16;
    m = 1;
    if constexpr (NJ > 8) inxt = *(const uint4*)(Ib + 8);
    hbs[J*64 + r] = hbits;            // hb[0]
  }
  BAR();

  for (int t = 1; t < 512; ++t){
    const int A0 = __builtin_ctz((unsigned)(t-1) | 256u);   // t-1==0 -> 8 -> all
    const int A = (A0 > 7) ? 7 : A0;
    const u32* hq0 = hbu + (((t-1)&1) << 8);

    if (J + 0 <= A) ctx[J+0] = gemv8(W0, hq0 + (J+0)*32);
    if constexpr (NB > 1){ if (J + 1 <= A) ctx[J+1] = gemv8(W1, hq0 + (J+1)*32); }
    if constexpr (NB > 2){ if (J + 2 <= A) ctx[J+2] = gemv8(W2, hq0 + (J+2)*32); }
    if constexpr (J <= 4){
      constexpr int CB = (J==0) ? 0 : (J==1) ? 5 : (J==2) ? 9 : (J==3) ? 12 : 14;
      #pragma unroll
      for (int dq = 3; dq < NB; ++dq){
        const int q = J + dq;
        if (q <= A) ctx[q] = gemv_lds(sWc + (CB + dq - 3)*2048 + r*32, hq0 + q*32, r & 7);
      }
    }

    if ((t & ((1 << J) - 1)) == 0){
      const int e = m & 7;
      if constexpr (NJ > 8){ if (e == 0 && m + 8 < NJ) inxt = *(const uint4*)(Ib + m + 8); }
      float z = cbv + f16at_rt(icur, e);
      #pragma unroll
      for (int q = J; q < 8; ++q) z += ctx[q];
      h = tanh_fast(z);
      const f16 h16 = (f16)h; hbits = __builtin_bit_cast(u16, h16);
      Hc[m*64 + r] = h16;
      if constexpr (NJ > 8){ if (e == 7) icur = inxt; }
      ++m;
    }
    hbs[((t&1) << 9) + J*64 + r] = hbits;   // current state, every step
    BAR();
  }
  Hout[(J*64 + r)*BB + b] = h;
}

__global__ __launch_bounds__(512) void cw_serial(
    const f16* __restrict__ Icomp, const u32* __restrict__ WhrP, const u32* __restrict__ WhlP,
    const float* __restrict__ cbg, f16* __restrict__ Hcomp, float* __restrict__ Hout)
{
  extern __shared__ u32 smem[];
  u32* sWc = smem;             // 30720 u32
  u32* hbu = smem + 30720;     // 512 u32 (2 x 512 f16)
  u16* hbs = (u16*)hbu;

  const int tid = (int)threadIdx.x;
  const int b   = (int)blockIdx.x;
  const int j   = tid >> 6, r = tid & 63;

  for (int i = tid; i < 30720; i += 512) sWc[i] = WhlP[i];

  const float cbv = cbg[tid];
  const int offh  = (1024 - (1024 >> j)) << 6;
  const f16* Ib = Icomp + (size_t)b*ICOMP_PER_B + offh + r*(512 >> j);
  f16* Hc = Hcomp + (size_t)b*ICOMP_PER_B + offh;

  switch (j){
    case 0: run_wave<0>(Ib, WhrP, sWc, hbu, hbs, Hc, Hout, cbv, r, b); break;
    case 1: run_wave<1>(Ib, WhrP, sWc, hbu, hbs, Hc, Hout, cbv, r, b); break;
    case 2: run_wave<2>(Ib, WhrP, sWc, hbu, hbs, Hc, Hout, cbv, r, b); break;
    case 3: run_wave<3>(Ib, WhrP, sWc, hbu, hbs, Hc, Hout, cbv, r, b); break;
    case 4: run_wave<4>(Ib, WhrP, sWc, hbu, hbs, Hc, Hout, cbv, r, b); break;
    case 5: run_wave<5>(Ib, WhrP, sWc, hbu, hbs, Hc, Hout, cbv, r, b); break;
    case 6: run_wave<6>(Ib, WhrP, sWc, hbu, hbs, Hc, Hout, cbv, r, b); break;
    default: run_wave<7>(Ib, WhrP, sWc, hbu, hbs, Hc, Hout, cbv, r, b); break;
  }
}

// ---------------- ygemm2: Y = tanh(Wo.H + b), time on the B-column axis ----------------
// One batch column per WG (512 thr, 8 waves); wave w handles o-rows [16w,16w+16).
// B-frag: lane col la = timestep -> Hcomp loads stride 128B (j=0) or broadcast (j>0).
// D lane (la,lb) holds o = o0+lb*4+reg (consecutive) at t = la -> one float4 store.
__global__ __launch_bounds__(512) void cw_ygemm2(
    const f16* __restrict__ Hcomp, const u32* __restrict__ WoAu,
    const float* __restrict__ wobg, float* __restrict__ Y)
{
  const int tid = (int)threadIdx.x;
  const int w = tid >> 6, l = tid & 63;
  const int la = l & 15, lb = l >> 4;
  const int b  = (int)blockIdx.x;
  const int t0 = (int)blockIdx.y * 64;
  const int o0 = w * 16;

  uint4 A[16];
  {
    const u32* ap = WoAu + (o0 + la)*256 + lb*4;
    #pragma unroll
    for (int ks = 0; ks < 16; ++ks) A[ks] = *(const uint4*)(ap + ks*16);
  }
  const float4 wv = *(const float4*)(wobg + o0 + lb*4);
  const f16* Hb = Hcomp + (size_t)b * ICOMP_PER_B;

  #pragma unroll
  for (int tt = 0; tt < 4; ++tt){
    const int tA = t0 + tt*16 + la;     // this lane's B-column time
    f32x4 ac = {0.f,0.f,0.f,0.f};
    #pragma unroll
    for (int ks = 0; ks < 16; ++ks){
      const int j   = ks >> 1;
      const int m   = tA >> j;
      const int off = ((1024 - (1024 >> j)) << 6) + (m << 6) + ((ks & 1) << 5) + lb*8;
      const uint4 Bf = *(const uint4*)(Hb + off);
      ac = __builtin_amdgcn_mfma_f32_16x16x32_f16(
             __builtin_bit_cast(f16x8, A[ks]), __builtin_bit_cast(f16x8, Bf), ac, 0,0,0);
    }
    float4 yv;
    yv.x = tanh_fast(ac[0] + wv.x);
    yv.y = tanh_fast(ac[1] + wv.y);
    yv.z = tanh_fast(ac[2] + wv.z);
    yv.w = tanh_fast(ac[3] + wv.w);
    *(float4*)(Y + ((size_t)(t0 + tt*16 + la)*BB + b)*NO_ + o0 + lb*4) = yv;
  }
}

extern "C" void kernel_launch(void* const* d_in, const int* in_sizes, int n_in,
                              void* d_out, int out_size, void* d_ws, size_t ws_size,
                              hipStream_t stream)
{
  const float* X  = (const float*)d_in[0];
  const float* Wi = (const float*)d_in[1];
  const float* Wh = (const float*)d_in[2];
  const float* Wo = (const float*)d_in[3];

  u32*   WiP  = (u32*)d_ws;
  u32*   WhrP = WiP  + WIP_N;
  u32*   WhlP = WhrP + WHRP_N;
  u32*   WoAu = WhlP + WHLP_N;
  float* cb   = (float*)(WoAu + WOA_N);
  float* wob  = cb + 512;
  f16*   Icomp = (f16*)(wob + 128);
  f16*   Hcomp = Icomp + (size_t)BB * ICOMP_PER_B;

  float* Y    = (float*)d_out;
  float* Hout = Y + (size_t)TT*BB*NO_;

  const int prep_n = WIP_N + WHRP_N + WHLP_N + WOA_N + 512 + 128;
  hipLaunchKernelGGL(cw_prep, dim3((prep_n + 255)/256), dim3(256), 0, stream,
                     Wi, Wh, Wo, WiP, WhrP, WhlP, WoAu, cb, wob);

  hipLaunchKernelGGL(cw_igemm, dim3(256*19), dim3(256), 0, stream, X, WiP, Icomp);

  hipFuncSetAttribute(reinterpret_cast<const void*>(cw_serial),
                      hipFuncAttributeMaxDynamicSharedMemorySize, SERIAL_LDS);
  hipLaunchKernelGGL(cw_serial, dim3(BB), dim3(512), SERIAL_LDS, stream,
                     Icomp, WhrP, WhlP, cb, Hcomp, Hout);

  hipLaunchKernelGGL(cw_ygemm2, dim3(BB, 8), dim3(512), 0, stream,
                     Hcomp, WoAu, wob, Y);
}